// Round 3
// baseline (292.706 us; speedup 1.0000x reference)
//
#include <hip/hip_runtime.h>

// R8: R7's VALU-diet STRUCTURE with R6's bit-exact NUMERICS.
// R7 failed (absmax 0.20) after changing two semantic things at once:
//   (a) layer-1 zeroing moved from B-side to A-side + unguarded loads,
//   (b) relu via inline-asm v_pk_max_f16.
// R8 reverts both to the R6-known-good forms while keeping the structural
// wins that attack R6's measured bottleneck (VALUBusy=82%, MfmaUtil=16%):
//   - TILES_PER_WAVE=25 (PTS_PER_BLOCK=1600; 1e6 = 625*1600 exactly -> the
//     fast path has zero bounds checks and no tail).
//   - 6 per-wave base pointers; tiles address via 13-bit imm offsets only
//     (64*t <= 1536B). No per-tile address arithmetic.
//   - loads are UNCONDITIONAL (addresses valid for all lanes; quads 1..3
//     duplicate quad 0's cachelines), and the layer-1 B-frag is zeroed for
//     quads>=1 with two v_cndmask per tile (isq0 ? packed : 0) — bitwise
//     identical to R6's exec-masked zero-init, cheaper to issue.
//   - a1 is quad-BROADCAST (same 4 halfs in all quads), exactly as R6.
//   - relu: fmaxf in f32 then cvt_pkrtz, exactly as R6.
//
// Frag layouts (16x16x16, CDNA family):
//   A[m][k]: lane m=lane&15, k = 4*(lane>>4) + j   (4 f16, 2 VGPRs)
//   B[k][n]: lane n=lane&15, k = 4*(lane>>4) + j
//   C/D:     lane n=lane&15, row = 4*(lane>>4) + i (4 fp32)
// Layer-1 correctness: B quads>=1 are true zeros, so a1's broadcast rows
// (k>=4 would-be values) contribute nothing. D-layout == next B-layout, so
// layer chaining is pure per-lane register work. Bias rides in the MFMA C
// operand (fp32, exact). Weights RNE-cast, activations RTZ — same as R5/R6.

#define MFMA16(a, b, c) __builtin_amdgcn_mfma_f32_16x16x16f16((a), (b), (c), 0, 0, 0)

#define TILES_PER_WAVE 25
#define WAVES_PER_BLOCK 4
#define PTS_PER_WAVE (TILES_PER_WAVE * 16)              // 400
#define PTS_PER_BLOCK (PTS_PER_WAVE * WAVES_PER_BLOCK)  // 1600; 1e6 = 625*1600

typedef __fp16 pk16x2 __attribute__((ext_vector_type(2)));   // cvt_pkrtz return type
typedef _Float16 half4_t __attribute__((ext_vector_type(4)));
typedef float float4_t __attribute__((ext_vector_type(4)));

union H2I { pk16x2 h; int i; };
union Frag { half4_t v; int i[2]; };

__device__ __forceinline__ int pkrtz(float a, float b) {
    H2I u; u.h = __builtin_amdgcn_cvt_pkrtz(a, b); return u.i;
}

__global__ __launch_bounds__(256) void fields_r8_kernel(
    const float* __restrict__ x,
    const float* __restrict__ W1, const float* __restrict__ b1,
    const float* __restrict__ W2, const float* __restrict__ b2,
    const float* __restrict__ W3, const float* __restrict__ b3,
    float* __restrict__ out, int N)
{
    const int lane = threadIdx.x & 63;
    const int wave = threadIdx.x >> 6;
    const int q    = lane >> 4;        // quad 0..3
    const int n16  = lane & 15;        // point within tile / row m for A

    const int d     = blockIdx.x & 15;
    const int chunk = blockIdx.x >> 4;
    const int base  = chunk * PTS_PER_BLOCK + wave * PTS_PER_WAVE;

    // ---- weights -> registers, frag-ready (once per wave), R6-exact ----
    Frag a1, a2, a3;
    {
        // a1: quad-broadcast {w0,w1,w2,0} (all quads identical, like R6).
        const float* w1 = W1 + (d * 16 + n16) * 3;
        a1.v = (half4_t){(_Float16)w1[0], (_Float16)w1[1],
                         (_Float16)w1[2], (_Float16)0.f};
        const float4_t w2 = *(const float4_t*)(W2 + (d * 16 + n16) * 16 + q * 4);
        a2.v = (half4_t){(_Float16)w2.x, (_Float16)w2.y, (_Float16)w2.z,
                         (_Float16)w2.w};
        if (n16 < 3) {
            const float4_t w3 = *(const float4_t*)(W3 + (d * 3 + n16) * 16 + q * 4);
            a3.v = (half4_t){(_Float16)w3.x, (_Float16)w3.y, (_Float16)w3.z,
                             (_Float16)w3.w};
        } else {
            a3.i[0] = 0; a3.i[1] = 0;
        }
    }
    const float4_t bias1 = *(const float4_t*)(b1 + d * 16 + q * 4);
    const float4_t bias2 = *(const float4_t*)(b2 + d * 16 + q * 4);
    float4_t bias3 = (float4_t){0.f, 0.f, 0.f, 0.f};
    if (q == 0) {
        bias3.x = b3[d * 3 + 0];
        bias3.y = b3[d * 3 + 1];
        bias3.z = b3[d * 3 + 2];
    }

    const bool isq0 = (q == 0);

    // ---- per-wave base pointers; tiles address via imm offsets only ----
    const float* xp0 = x + base + n16;
    const float* xp1 = xp0 + N;
    const float* xp2 = xp1 + N;
    float* op0 = out + (size_t)(d * 3 + 0) * N + base + n16;
    float* op1 = out + (size_t)(d * 3 + 1) * N + base + n16;
    float* op2 = out + (size_t)(d * 3 + 2) * N + base + n16;

    if (base + PTS_PER_WAVE <= N) {
        // fast path: no bounds checks anywhere
#pragma unroll
        for (int t = 0; t < TILES_PER_WAVE; ++t) {
            const int off = t * 16;
            // unconditional loads (valid addresses for all 64 lanes; quads
            // 1..3 re-read quad 0's cachelines — L1 broadcast, no HBM cost)
            const float x0 = xp0[off];
            const float x1 = xp1[off];
            const float x2 = xp2[off];
            // B-frag: quads>=1 forced to zero via cndmask (R6 semantics)
            const int p01 = pkrtz(x0, x1);
            const int p2  = pkrtz(x2, 0.f);
            Frag xf;
            xf.i[0] = isq0 ? p01 : 0;
            xf.i[1] = isq0 ? p2  : 0;

            // Layer 1: h1 = relu(W1 x + b1)   (D-layout == next B-layout)
            float4_t acc = MFMA16(a1.v, xf.v, bias1);
            Frag bf;
            bf.i[0] = pkrtz(fmaxf(acc.x, 0.f), fmaxf(acc.y, 0.f));
            bf.i[1] = pkrtz(fmaxf(acc.z, 0.f), fmaxf(acc.w, 0.f));
            // Layer 2
            acc = MFMA16(a2.v, bf.v, bias2);
            Frag cf;
            cf.i[0] = pkrtz(fmaxf(acc.x, 0.f), fmaxf(acc.y, 0.f));
            cf.i[1] = pkrtz(fmaxf(acc.z, 0.f), fmaxf(acc.w, 0.f));
            // Layer 3 (no relu); quad 0 rows 0..2 -> outputs of point n16
            acc = MFMA16(a3.v, cf.v, bias3);
            if (isq0) {
                op0[off] = acc.x;
                op1[off] = acc.y;
                op2[off] = acc.z;
            }
        }
    } else {
        // tail path (never taken for N=1e6): R6-style guarded loads/stores
#pragma unroll 1
        for (int t = 0; t < TILES_PER_WAVE; ++t) {
            const int off = t * 16;
            const int pt = base + off + n16;
            float x0 = 0.f, x1 = 0.f, x2 = 0.f;
            if (isq0 && pt < N) {
                x0 = xp0[off];
                x1 = xp1[off];
                x2 = xp2[off];
            }
            Frag xf;
            xf.i[0] = pkrtz(x0, x1);
            xf.i[1] = pkrtz(x2, 0.f);

            float4_t acc = MFMA16(a1.v, xf.v, bias1);
            Frag bf;
            bf.i[0] = pkrtz(fmaxf(acc.x, 0.f), fmaxf(acc.y, 0.f));
            bf.i[1] = pkrtz(fmaxf(acc.z, 0.f), fmaxf(acc.w, 0.f));

            acc = MFMA16(a2.v, bf.v, bias2);
            Frag cf;
            cf.i[0] = pkrtz(fmaxf(acc.x, 0.f), fmaxf(acc.y, 0.f));
            cf.i[1] = pkrtz(fmaxf(acc.z, 0.f), fmaxf(acc.w, 0.f));

            acc = MFMA16(a3.v, cf.v, bias3);
            if (isq0 && pt < N) {
                op0[off] = acc.x;
                op1[off] = acc.y;
                op2[off] = acc.z;
            }
        }
    }
}

extern "C" void kernel_launch(void* const* d_in, const int* in_sizes, int n_in,
                              void* d_out, int out_size, void* d_ws, size_t ws_size,
                              hipStream_t stream) {
    const float* x  = (const float*)d_in[0];
    const float* W1 = (const float*)d_in[1];
    const float* b1 = (const float*)d_in[2];
    const float* W2 = (const float*)d_in[3];
    const float* b2 = (const float*)d_in[4];
    const float* W3 = (const float*)d_in[5];
    const float* b3 = (const float*)d_in[6];
    float* out = (float*)d_out;

    const int N = in_sizes[0] / 3;  // x is [1,3,N]
    const int chunks = (N + PTS_PER_BLOCK - 1) / PTS_PER_BLOCK;
    const int grid = chunks * 16;   // 16 fields in the low bits
    fields_r8_kernel<<<grid, 256, 0, stream>>>(x, W1, b1, W2, b2, W3, b3, out, N);
}

// Round 4
// 260.673 us; speedup vs baseline: 1.1229x; 1.1229x over previous
//
#include <hip/hip_runtime.h>

// R9: latency attack. R8's counters (dur unchanged vs R6 despite VALUBusy
// 82->55%, HBM 23%, MfmaUtil 15%, VGPR=24) => latency-bound with a serial
// per-tile schedule (compiler register-minimized the unroll: 1 load in
// flight, 3 dependent MFMAs per tile) and L2-missing x loads (FETCH=4x x:
// current map puts same-chunk blocks on XCD d%8, all 8 XCDs fetch x).
//
// Changes vs R8 (numerics bit-identical; pure reordering + index remap):
//  - 25 tiles = 5 groups x 5, processed LAYER-WISE with explicit
//    double-buffered prefetch xb[2][3][5]: group g+1's 15 loads issue
//    before group g is consumed -> ~15 loads in flight, 5-way MFMA ILP.
//    All indices compile-time constants (static indexing, no scratch).
//  - XCD swizzle: blockIdx = r + 8*d + 128*a, chunk = 8a + r -> all 16
//    d-blocks of a chunk land on XCD chunk%8 within a 128-block dispatch
//    window -> x loads become L2 hits. (Verify via FETCH_SIZE ~15 MB.)
//
// Frag layouts (16x16x16, CDNA family):
//   A[m][k]: lane m=lane&15, k = 4*(lane>>4) + j   (4 f16, 2 VGPRs)
//   B[k][n]: lane n=lane&15, k = 4*(lane>>4) + j
//   C/D:     lane n=lane&15, row = 4*(lane>>4) + i (4 fp32)
// Layer-1: B quads>=1 forced to zero (cndmask), a1 quad-broadcast (R6/R8
// known-good). D-layout == next B-layout -> chaining is per-lane register
// work. Bias rides in MFMA C operand (fp32). Weights RNE, activations RTZ.

#define MFMA16(a, b, c) __builtin_amdgcn_mfma_f32_16x16x16f16((a), (b), (c), 0, 0, 0)

#define GP 5                      // tiles per group
#define NG 5                      // groups per wave
#define TILES_PER_WAVE (GP * NG)  // 25
#define WAVES_PER_BLOCK 4
#define PTS_PER_WAVE (TILES_PER_WAVE * 16)              // 400
#define PTS_PER_BLOCK (PTS_PER_WAVE * WAVES_PER_BLOCK)  // 1600; 1e6 = 625*1600

typedef __fp16 pk16x2 __attribute__((ext_vector_type(2)));   // cvt_pkrtz return type
typedef _Float16 half4_t __attribute__((ext_vector_type(4)));
typedef float float4_t __attribute__((ext_vector_type(4)));

union H2I { pk16x2 h; int i; };
union Frag { half4_t v; int i[2]; };

__device__ __forceinline__ int pkrtz(float a, float b) {
    H2I u; u.h = __builtin_amdgcn_cvt_pkrtz(a, b); return u.i;
}

__global__ __launch_bounds__(256) void fields_r9_kernel(
    const float* __restrict__ x,
    const float* __restrict__ W1, const float* __restrict__ b1,
    const float* __restrict__ W2, const float* __restrict__ b2,
    const float* __restrict__ W3, const float* __restrict__ b3,
    float* __restrict__ out, int N)
{
    const int lane = threadIdx.x & 63;
    const int wave = threadIdx.x >> 6;
    const int q    = lane >> 4;        // quad 0..3
    const int n16  = lane & 15;        // point within tile / row m for A

    // ---- XCD-swizzled decode: chunk c = 8a + r runs on XCD r = c%8 ----
    const int bid = blockIdx.x;
    const int r   = bid & 7;
    const int d   = (bid >> 3) & 15;
    const int a   = bid >> 7;
    const int chunk  = a * 8 + r;
    const int chunks = (N + PTS_PER_BLOCK - 1) / PTS_PER_BLOCK;
    if (chunk >= chunks) return;       // pad blocks (grid rounded to *8)

    const int base = chunk * PTS_PER_BLOCK + wave * PTS_PER_WAVE;

    // ---- weights -> registers, frag-ready (once per wave), R8-exact ----
    Frag a1, a2, a3;
    {
        const float* w1 = W1 + (d * 16 + n16) * 3;
        a1.v = (half4_t){(_Float16)w1[0], (_Float16)w1[1],
                         (_Float16)w1[2], (_Float16)0.f};
        const float4_t w2 = *(const float4_t*)(W2 + (d * 16 + n16) * 16 + q * 4);
        a2.v = (half4_t){(_Float16)w2.x, (_Float16)w2.y, (_Float16)w2.z,
                         (_Float16)w2.w};
        if (n16 < 3) {
            const float4_t w3 = *(const float4_t*)(W3 + (d * 3 + n16) * 16 + q * 4);
            a3.v = (half4_t){(_Float16)w3.x, (_Float16)w3.y, (_Float16)w3.z,
                             (_Float16)w3.w};
        } else {
            a3.i[0] = 0; a3.i[1] = 0;
        }
    }
    const float4_t bias1 = *(const float4_t*)(b1 + d * 16 + q * 4);
    const float4_t bias2 = *(const float4_t*)(b2 + d * 16 + q * 4);
    float4_t bias3 = (float4_t){0.f, 0.f, 0.f, 0.f};
    if (q == 0) {
        bias3.x = b3[d * 3 + 0];
        bias3.y = b3[d * 3 + 1];
        bias3.z = b3[d * 3 + 2];
    }

    const bool isq0 = (q == 0);

    // ---- per-wave base pointers; tiles address via imm offsets only ----
    const float* xp0 = x + base + n16;
    const float* xp1 = xp0 + N;
    const float* xp2 = xp1 + N;
    float* op0 = out + (size_t)(d * 3 + 0) * N + base + n16;
    float* op1 = out + (size_t)(d * 3 + 1) * N + base + n16;
    float* op2 = out + (size_t)(d * 3 + 2) * N + base + n16;

    if (base + PTS_PER_WAVE <= N) {
        // ===== fast path: grouped, layer-wise, double-buffered prefetch ====
        float xb[2][3][GP];   // [buf][row][tile] — all indices compile-time
#pragma unroll
        for (int t = 0; t < GP; ++t) {         // prologue: load group 0
            xb[0][0][t] = xp0[t * 16];
            xb[0][1][t] = xp1[t * 16];
            xb[0][2][t] = xp2[t * 16];
        }
#pragma unroll
        for (int g = 0; g < NG; ++g) {
            const int b = g & 1;               // compile-time after unroll
            if (g + 1 < NG) {                  // prefetch group g+1
                const int nb = (g + 1) & 1;
#pragma unroll
                for (int t = 0; t < GP; ++t) {
                    const int off = ((g + 1) * GP + t) * 16;
                    xb[nb][0][t] = xp0[off];
                    xb[nb][1][t] = xp1[off];
                    xb[nb][2][t] = xp2[off];
                }
            }
            // pack x -> B-frags (quads>=1 zeroed: R8 semantics)
            Frag xf[GP];
#pragma unroll
            for (int t = 0; t < GP; ++t) {
                const int p01 = pkrtz(xb[b][0][t], xb[b][1][t]);
                const int p2  = pkrtz(xb[b][2][t], 0.f);
                xf[t].i[0] = isq0 ? p01 : 0;
                xf[t].i[1] = isq0 ? p2  : 0;
            }
            // layer 1 (5 independent MFMAs)
            float4_t acc[GP];
#pragma unroll
            for (int t = 0; t < GP; ++t) acc[t] = MFMA16(a1.v, xf[t].v, bias1);
            Frag hf[GP];
#pragma unroll
            for (int t = 0; t < GP; ++t) {
                hf[t].i[0] = pkrtz(fmaxf(acc[t].x, 0.f), fmaxf(acc[t].y, 0.f));
                hf[t].i[1] = pkrtz(fmaxf(acc[t].z, 0.f), fmaxf(acc[t].w, 0.f));
            }
            // layer 2
#pragma unroll
            for (int t = 0; t < GP; ++t) acc[t] = MFMA16(a2.v, hf[t].v, bias2);
#pragma unroll
            for (int t = 0; t < GP; ++t) {
                hf[t].i[0] = pkrtz(fmaxf(acc[t].x, 0.f), fmaxf(acc[t].y, 0.f));
                hf[t].i[1] = pkrtz(fmaxf(acc[t].z, 0.f), fmaxf(acc[t].w, 0.f));
            }
            // layer 3 (no relu)
#pragma unroll
            for (int t = 0; t < GP; ++t) acc[t] = MFMA16(a3.v, hf[t].v, bias3);
            if (isq0) {
#pragma unroll
                for (int t = 0; t < GP; ++t) {
                    const int off = (g * GP + t) * 16;
                    op0[off] = acc[t].x;
                    op1[off] = acc[t].y;
                    op2[off] = acc[t].z;
                }
            }
        }
    } else {
        // tail path (never taken for N=1e6): R8-style guarded serial tiles
#pragma unroll 1
        for (int t = 0; t < TILES_PER_WAVE; ++t) {
            const int off = t * 16;
            const int pt = base + off + n16;
            float x0 = 0.f, x1 = 0.f, x2 = 0.f;
            if (isq0 && pt < N) {
                x0 = xp0[off];
                x1 = xp1[off];
                x2 = xp2[off];
            }
            Frag xf;
            xf.i[0] = pkrtz(x0, x1);
            xf.i[1] = pkrtz(x2, 0.f);

            float4_t acc = MFMA16(a1.v, xf.v, bias1);
            Frag bf;
            bf.i[0] = pkrtz(fmaxf(acc.x, 0.f), fmaxf(acc.y, 0.f));
            bf.i[1] = pkrtz(fmaxf(acc.z, 0.f), fmaxf(acc.w, 0.f));

            acc = MFMA16(a2.v, bf.v, bias2);
            Frag cf;
            cf.i[0] = pkrtz(fmaxf(acc.x, 0.f), fmaxf(acc.y, 0.f));
            cf.i[1] = pkrtz(fmaxf(acc.z, 0.f), fmaxf(acc.w, 0.f));

            acc = MFMA16(a3.v, cf.v, bias3);
            if (isq0 && pt < N) {
                op0[off] = acc.x;
                op1[off] = acc.y;
                op2[off] = acc.z;
            }
        }
    }
}

extern "C" void kernel_launch(void* const* d_in, const int* in_sizes, int n_in,
                              void* d_out, int out_size, void* d_ws, size_t ws_size,
                              hipStream_t stream) {
    const float* x  = (const float*)d_in[0];
    const float* W1 = (const float*)d_in[1];
    const float* b1 = (const float*)d_in[2];
    const float* W2 = (const float*)d_in[3];
    const float* b2 = (const float*)d_in[4];
    const float* W3 = (const float*)d_in[5];
    const float* b3 = (const float*)d_in[6];
    float* out = (float*)d_out;

    const int N = in_sizes[0] / 3;  // x is [1,3,N]
    const int chunks = (N + PTS_PER_BLOCK - 1) / PTS_PER_BLOCK;   // 625
    const int a_max  = (chunks + 7) / 8;                          // 79
    const int grid   = 8 * 16 * a_max;                            // 10112
    fields_r9_kernel<<<grid, 256, 0, stream>>>(x, W1, b1, W2, b2, W3, b3, out, N);
}